// Round 2
// baseline (45999.887 us; speedup 1.0000x reference)
//
#include <hip/hip_runtime.h>
#include <hip/hip_bf16.h>
#include <stdint.h>

// Problem dims
#define TD   1000
#define BB   64
#define HH   1024
#define EE   512
#define MMEL 80
#define TMEL 2000
#define RTOT (TD*BB)   // 64000 rows, row index = t*64 + b

typedef __attribute__((ext_vector_type(8))) short short8;   // 8 bf16 (4 VGPRs)
typedef __attribute__((ext_vector_type(4))) float f32x4;

__device__ __forceinline__ float bf2f(uint16_t h){ return __uint_as_float(((uint32_t)h)<<16); }
__device__ __forceinline__ uint16_t f2bf(float f){
  uint32_t u = __float_as_uint(f);
  return (uint16_t)((u + 0x7fffu + ((u>>16)&1u)) >> 16);   // RTNE
}

__device__ __forceinline__ void async16(const void* g, void* l) {
  __builtin_amdgcn_global_load_lds((const __attribute__((address_space(1))) void*)g,
                                   (__attribute__((address_space(3))) void*)l, 16, 0, 0);
}

__device__ __forceinline__ f32x4 mfma16(short8 a, short8 b, f32x4 c){
  return __builtin_amdgcn_mfma_f32_16x16x32_bf16(a, b, c, 0, 0, 0);
}

// ---------------- small prep kernels ----------------

__global__ void k_zero16(uint16_t* p, int n){ int i=blockIdx.x*256+threadIdx.x; if(i<n) p[i]=0; }
__global__ void k_zero32(unsigned* p, int n){ int i=blockIdx.x*256+threadIdx.x; if(i<n) p[i]=0u; }
__global__ void k_fill(float* p, int n, float v){ int i=blockIdx.x*256+threadIdx.x; if(i<n) p[i]=v; }

// f32 -> bf16 slice/pad copy. dst[r, c] = (c<cols)? src[r*src_ld + col0 + c] : 0
__global__ void k_cast(const float* __restrict__ src, uint16_t* __restrict__ dst,
                       int rows, int src_ld, int col0, int cols, int dst_ld){
  int i = blockIdx.x*256 + threadIdx.x;
  if (i >= rows*dst_ld) return;
  int r = i/dst_ld, c = i - r*dst_ld;
  float v = (c < cols) ? src[(size_t)r*src_ld + col0 + c] : 0.f;
  dst[i] = f2bf(v);
}

// teacher-forced decoder inputs, padded K=96: row t*64+b, di[t]= t==0?0:dec[b, 2t-1, :]
__global__ void k_di(const float* __restrict__ dec, uint16_t* __restrict__ di){
  int i = blockIdx.x*256 + threadIdx.x;
  if (i >= RTOT*96) return;
  int row = i/96, c = i - row*96;
  int t = row>>6, b = row&63;
  float v = 0.f;
  if (c < MMEL && t > 0) v = dec[((size_t)b*TMEL + (2*t-1))*MMEL + c];
  di[i] = f2bf(v);
}

// pooled memory: MEM[t*64+b, e] = 0.5*(memorys[b,2t,e]+memorys[b,2t+1,e])
__global__ void k_mem(const float* __restrict__ mem, uint16_t* __restrict__ out){
  int i = blockIdx.x*256 + threadIdx.x;
  if (i >= RTOT*EE) return;
  int row = i/EE, e = i - row*EE;
  int t = row>>6, b = row&63;
  size_t base = ((size_t)b*TMEL + 2*t)*EE + e;
  out[i] = f2bf(0.5f*(mem[base] + mem[base+EE]));
}

// ---------------- tiled bf16 MFMA GEMM ----------------
// C[M,N] = [A1 | A2][M, K1+K2] @ B[N,K]^T (+bias)(+Dadd)(relu?)
// M = 64000 (500 full 128-tiles, blockIdx.y). OM: 0 bf16 linear, 1 f32 remap (b,t), 2 f32 linear.
// DT: Dadd dtype 0 bf16, 1 f32.

template<int OM, int DT>
__global__ __launch_bounds__(256)
void k_gemm(const uint16_t* __restrict__ A1p, int K1, int lda1,
            const uint16_t* __restrict__ A2p, int K2, int lda2,
            const uint16_t* __restrict__ Bw, int ldb,
            void* __restrict__ Cp, int ldc,
            const float* __restrict__ bias,
            const void* __restrict__ Dadd, int ldd,
            int N, int relu)
{
  __shared__ __align__(16) uint16_t As[128*32];
  __shared__ __align__(16) uint16_t Bs[128*32];
  const int tid = threadIdx.x;
  const int w = tid>>6, lane = tid&63;
  const int q = lane>>4, ln = lane&15;
  const int m0 = blockIdx.y*128, n0 = blockIdx.x*128;
  const int wr = (w&1)*64, wc = (w>>1)*64;
  const int srow = w*32 + (lane>>2);
  const int scol = (lane&3)*8;
  const uint16_t* A1g = A1p + (size_t)(m0+srow)*lda1 + scol;
  const uint16_t* A1g2 = A1g + (size_t)16*lda1;
  const uint16_t* A2g = A2p ? A2p + (size_t)(m0+srow)*lda2 + scol : nullptr;
  const uint16_t* A2g2 = A2p ? A2g + (size_t)16*lda2 : nullptr;
  int bn1 = n0+srow;     bn1 = bn1 < N ? bn1 : N-1;
  int bn2 = n0+srow+16;  bn2 = bn2 < N ? bn2 : N-1;
  const uint16_t* Bg  = Bw + (size_t)bn1*ldb + scol;
  const uint16_t* Bg2 = Bw + (size_t)bn2*ldb + scol;
  uint16_t* As0 = &As[(w*32)*32];
  uint16_t* As1 = &As[(w*32+16)*32];
  uint16_t* Bs0 = &Bs[(w*32)*32];
  uint16_t* Bs1 = &Bs[(w*32+16)*32];
  const int K = K1 + K2;

  f32x4 acc[4][4] = {};
  for (int kt=0; kt<K; kt+=32) {
    __syncthreads();
    if (kt < K1) { async16(A1g+kt, As0);  async16(A1g2+kt, As1); }
    else         { async16(A2g+(kt-K1), As0);  async16(A2g2+(kt-K1), As1); }
    async16(Bg+kt, Bs0);  async16(Bg2+kt, Bs1);
    __syncthreads();
    short8 af[4], bfr[4];
    #pragma unroll
    for (int i=0;i<4;++i) af[i]  = *(const short8*)&As[(wr+16*i+ln)*32 + q*8];
    #pragma unroll
    for (int j=0;j<4;++j) bfr[j] = *(const short8*)&Bs[(wc+16*j+ln)*32 + q*8];
    #pragma unroll
    for (int i=0;i<4;++i)
      #pragma unroll
      for (int j=0;j<4;++j)
        acc[i][j] = mfma16(af[i], bfr[j], acc[i][j]);
  }

  #pragma unroll
  for (int i=0;i<4;++i){
    #pragma unroll
    for (int j=0;j<4;++j){
      int col = n0 + wc + 16*j + ln;
      if (col >= N) continue;
      float bv = bias ? bias[col] : 0.f;
      #pragma unroll
      for (int r=0;r<4;++r){
        int row = m0 + wr + 16*i + 4*q + r;
        float v = acc[i][j][r] + bv;
        if (Dadd) {
          if (DT) v += ((const float*)Dadd)[(size_t)row*ldd + col];
          else    v += bf2f(((const uint16_t*)Dadd)[(size_t)row*ldd + col]);
        }
        if (relu) v = v > 0.f ? v : 0.f;
        if (OM==0) {
          ((uint16_t*)Cp)[(size_t)row*ldc + col] = f2bf(v);
        } else if (OM==1) {
          int t = row>>6, b = row&63;
          ((float*)Cp)[((size_t)b*TD + t)*ldc + col] = v;
        } else {
          ((float*)Cp)[(size_t)row*ldc + col] = v;
        }
      }
    }
  }
}

// ---------------- grid barrier (64 co-resident blocks, agent scope) ----------------

__device__ __forceinline__ void gridbar(unsigned* bar, unsigned nb){
  __syncthreads();
  if (threadIdx.x == 0) {
    __threadfence();   // release: make this block's stores device-visible
    unsigned g = __hip_atomic_load(bar+1, __ATOMIC_RELAXED, __HIP_MEMORY_SCOPE_AGENT);
    unsigned a = __hip_atomic_fetch_add(bar, 1u, __ATOMIC_ACQ_REL, __HIP_MEMORY_SCOPE_AGENT);
    if (a == nb-1u) {
      __hip_atomic_store(bar,   0u,   __ATOMIC_RELAXED, __HIP_MEMORY_SCOPE_AGENT);
      __hip_atomic_store(bar+1, g+1u, __ATOMIC_RELEASE, __HIP_MEMORY_SCOPE_AGENT);
    } else {
      while (__hip_atomic_load(bar+1, __ATOMIC_RELAXED, __HIP_MEMORY_SCOPE_AGENT) == g)
        __builtin_amdgcn_s_sleep(2);
    }
    __threadfence();   // acquire: invalidate stale cached lines
  }
  __syncthreads();
}

// ---------------- persistent GRU recurrence pass ----------------
// 64 blocks x 256 threads. Block owns 16 h-columns (j = blk*16 + ln) for all 64 batches.
// whh slice (3 gates x 16 cols x 1024 K) preloaded into registers.

__global__ __launch_bounds__(256,1)
void k_rec(const uint16_t* __restrict__ whh, const float* __restrict__ bhh,
           const uint16_t* __restrict__ gi, uint16_t* __restrict__ h_all,
           const uint16_t* __restrict__ radd, uint16_t* __restrict__ rout,
           int ld_rout, unsigned* bar)
{
  __shared__ __align__(16) float red[12288];   // 48 slots x 64 lanes x 4 regs
  const int tid = threadIdx.x;
  const int w = tid>>6, lane = tid&63;
  const int q = lane>>4, ln = lane&15;
  const int j = blockIdx.x*16 + ln;
  const float bh0 = bhh[j], bh1 = bhh[1024+j], bh2 = bhh[2048+j];

  short8 breg[3][8];
  #pragma unroll
  for (int g=0; g<3; ++g) {
    const uint16_t* Bp = whh + (size_t)(g*1024 + j)*1024 + (w*8)*32 + q*8;
    #pragma unroll
    for (int ks=0; ks<8; ++ks)
      breg[g][ks] = *(const short8*)(Bp + ks*32);
  }

  float hold[4] = {0.f,0.f,0.f,0.f};

  for (int t=0; t<TD; ++t) {
    const uint16_t* hp = h_all + (size_t)t*(BB*HH);
    f32x4 acc[3][4];
    #pragma unroll
    for (int g=0;g<3;++g)
      #pragma unroll
      for (int mt=0;mt<4;++mt) acc[g][mt] = (f32x4){0.f,0.f,0.f,0.f};

    #pragma unroll
    for (int ks=0; ks<8; ++ks) {
      const int k0 = (w*8+ks)*32 + q*8;
      #pragma unroll
      for (int mt=0; mt<4; ++mt) {
        short8 a = *(const short8*)(hp + (size_t)(16*mt+ln)*HH + k0);
        acc[0][mt] = mfma16(a, breg[0][ks], acc[0][mt]);
        acc[1][mt] = mfma16(a, breg[1][ks], acc[1][mt]);
        acc[2][mt] = mfma16(a, breg[2][ks], acc[2][mt]);
      }
    }

    #pragma unroll
    for (int g=0;g<3;++g)
      #pragma unroll
      for (int mt=0;mt<4;++mt)
        *(f32x4*)&red[((w*12 + g*4 + mt)*64 + lane)*4] = acc[g][mt];
    __syncthreads();

    f32x4 s0, s1, s2;
    s0 = *(const f32x4*)&red[((0*12 + 0*4 + w)*64 + lane)*4];
    s1 = *(const f32x4*)&red[((0*12 + 1*4 + w)*64 + lane)*4];
    s2 = *(const f32x4*)&red[((0*12 + 2*4 + w)*64 + lane)*4];
    #pragma unroll
    for (int kw=1;kw<4;++kw){
      s0 += *(const f32x4*)&red[((kw*12 + 0*4 + w)*64 + lane)*4];
      s1 += *(const f32x4*)&red[((kw*12 + 1*4 + w)*64 + lane)*4];
      s2 += *(const f32x4*)&red[((kw*12 + 2*4 + w)*64 + lane)*4];
    }

    #pragma unroll
    for (int r=0;r<4;++r){
      const int b = 16*w + 4*q + r;
      const size_t rowi = (size_t)t*BB + b;
      const size_t gb = rowi*3072;
      float ir  = bf2f(gi[gb + j]);
      float iz  = bf2f(gi[gb + 1024 + j]);
      float inn = bf2f(gi[gb + 2048 + j]);
      float rg = 1.f/(1.f + __expf(-(ir + s0[r] + bh0)));
      float zg = 1.f/(1.f + __expf(-(iz + s1[r] + bh1)));
      float nx = inn + rg*(s2[r] + bh2);
      float ng = 1.f - 2.f/(1.f + __expf(2.f*nx));   // tanh(nx)
      float hn = (1.f - zg)*ng + zg*hold[r];
      hold[r] = hn;
      h_all[(size_t)(t+1)*(BB*HH) + (size_t)b*HH + j] = f2bf(hn);
      if (rout) {
        float rv = hn + bf2f(radd[rowi*HH + j]);
        rout[rowi*(size_t)ld_rout + j] = f2bf(rv);
      }
    }
    gridbar(bar, 64u);
  }
}

// ---------------- host launch ----------------

extern "C" void kernel_launch(void* const* d_in, const int* in_sizes, int n_in,
                              void* d_out, int out_size, void* d_ws, size_t ws_size,
                              hipStream_t stream)
{
  (void)in_sizes; (void)n_in;
  const float* memorys = (const float*)d_in[0];
  const float* decin   = (const float*)d_in[1];
  const float* pre_w1  = (const float*)d_in[3];
  const float* pre_b1  = (const float*)d_in[4];
  const float* pre_w2  = (const float*)d_in[5];
  const float* pre_b2  = (const float*)d_in[6];
  const float* g1_wih  = (const float*)d_in[7];
  const float* g1_whh  = (const float*)d_in[8];
  const float* g1_bih  = (const float*)d_in[9];
  const float* g1_bhh  = (const float*)d_in[10];
  const float* att_w   = (const float*)d_in[11];
  const float* att_b   = (const float*)d_in[12];
  const float* g2_wih  = (const float*)d_in[13];
  const float* g2_whh  = (const float*)d_in[14];
  const float* g2_bih  = (const float*)d_in[15];
  const float* g2_bhh  = (const float*)d_in[16];
  const float* g3_wih  = (const float*)d_in[17];
  const float* g3_whh  = (const float*)d_in[18];
  const float* g3_bih  = (const float*)d_in[19];
  const float* g3_bhh  = (const float*)d_in[20];
  const float* proj_w  = (const float*)d_in[21];
  const float* proj_b  = (const float*)d_in[22];

  uint16_t* ws = (uint16_t*)d_ws;
  size_t off = 0;
  auto alloc = [&](size_t n){ uint16_t* p = ws + off; off += (n + 127) & ~size_t(127); return p; };

  // weights (bf16)
  uint16_t* wG1WHH = alloc((size_t)3072*1024);
  uint16_t* wATTWH = alloc((size_t)1024*1024);
  uint16_t* wATTWM = alloc((size_t)1024*512);
  uint16_t* wG2WIH = alloc((size_t)3072*1024);
  uint16_t* wG2WHH = alloc((size_t)3072*1024);
  uint16_t* wG3WIH = alloc((size_t)3072*1024);
  uint16_t* wG3WHH = alloc((size_t)3072*1024);
  uint16_t* wG1WIH = alloc((size_t)3072*768);
  uint16_t* wPW1   = alloc((size_t)256*96);
  uint16_t* wPW2   = alloc((size_t)256*256);
  uint16_t* wPROJr = alloc((size_t)160*1024);
  uint16_t* wPROJm = alloc((size_t)160*512);

  float*    PM  = (float*)alloc((size_t)RTOT*160*2);       // f32 mem@projW_m^T + proj_b
  uint16_t* GI  = alloc((size_t)RTOT*3072);                // gi1 -> gi2 -> gi3
  uint16_t* B1  = alloc((size_t)(RTOT+BB)*1024);           // MEM -> h1_all -> R2A
  uint16_t* B2  = alloc((size_t)(RTOT+BB)*1024);           // attpre -> h2_all -> R3
  uint16_t* B3  = alloc((size_t)(RTOT+BB)*1024);           // X2 -> d2 -> h3_all
  unsigned* bar = (unsigned*)(ws + off); off += 128;

  // sub-lifetime aliases
  uint16_t* DI96 = GI;                       // 64000x96, dead before GI written
  uint16_t* X1   = GI + (size_t)6144000;     // 64000x256, dead before GI written
  uint16_t* MEM  = B1;                       // 64000x512
  uint16_t* X2   = B3;                       // 64000x256

  size_t need_bytes = off * 2;
  if (ws_size < need_bytes) {
    // diagnostic sentinel: encodes available workspace MB
    float v = 1048576.0f + (float)(ws_size >> 20);
    k_fill<<<dim3((out_size+255)/256), dim3(256), 0, stream>>>((float*)d_out, out_size, v);
    return;
  }

  auto NB = [](long long n){ return dim3((unsigned)((n+255)/256)); };

  // weight conversion / split / pad
  k_cast<<<NB(3072*1024), dim3(256), 0, stream>>>(g1_whh, wG1WHH, 3072, 1024, 0, 1024, 1024);
  k_cast<<<NB(1024*1024), dim3(256), 0, stream>>>(att_w,  wATTWH, 1024, 1536, 0, 1024, 1024);
  k_cast<<<NB(1024*512),  dim3(256), 0, stream>>>(att_w,  wATTWM, 1024, 1536, 1024, 512, 512);
  k_cast<<<NB(3072*1024), dim3(256), 0, stream>>>(g2_wih, wG2WIH, 3072, 1024, 0, 1024, 1024);
  k_cast<<<NB(3072*1024), dim3(256), 0, stream>>>(g2_whh, wG2WHH, 3072, 1024, 0, 1024, 1024);
  k_cast<<<NB(3072*1024), dim3(256), 0, stream>>>(g3_wih, wG3WIH, 3072, 1024, 0, 1024, 1024);
  k_cast<<<NB(3072*1024), dim3(256), 0, stream>>>(g3_whh, wG3WHH, 3072, 1024, 0, 1024, 1024);
  k_cast<<<NB(3072*768),  dim3(256), 0, stream>>>(g1_wih, wG1WIH, 3072, 768, 0, 768, 768);
  k_cast<<<NB(256*96),    dim3(256), 0, stream>>>(pre_w1, wPW1,   256, 80, 0, 80, 96);
  k_cast<<<NB(256*256),   dim3(256), 0, stream>>>(pre_w2, wPW2,   256, 256, 0, 256, 256);
  k_cast<<<NB(160*1024),  dim3(256), 0, stream>>>(proj_w, wPROJr, 160, 1536, 0, 1024, 1024);
  k_cast<<<NB(160*512),   dim3(256), 0, stream>>>(proj_w, wPROJm, 160, 1536, 1024, 512, 512);

  // inputs
  k_di <<<NB((long long)RTOT*96),  dim3(256), 0, stream>>>(decin, DI96);
  k_mem<<<NB((long long)RTOT*EE),  dim3(256), 0, stream>>>(memorys, MEM);
  k_zero32<<<dim3(1), dim3(64), 0, stream>>>(bar, 8);

  // prenet
  k_gemm<0,0><<<dim3(2,500), dim3(256), 0, stream>>>(DI96,96,96, nullptr,0,0, wPW1,96, X1,256, pre_b1, nullptr,0, 256, 1);
  k_gemm<0,0><<<dim3(2,500), dim3(256), 0, stream>>>(X1,256,256, nullptr,0,0, wPW2,256, X2,256, pre_b2, nullptr,0, 256, 1);

  // gi1 = [x|mem]@g1_wih^T + g1_bih
  k_gemm<0,0><<<dim3(24,500), dim3(256), 0, stream>>>(X2,256,256, MEM,512,512, wG1WIH,768, GI,3072, g1_bih, nullptr,0, 3072, 0);
  // attpre = mem@att_wm^T + att_b  -> B2
  k_gemm<0,0><<<dim3(8,500), dim3(256), 0, stream>>>(MEM,512,512, nullptr,0,0, wATTWM,512, B2,1024, att_b, nullptr,0, 1024, 0);
  // PM = mem@proj_wm^T + proj_b (f32)
  k_gemm<2,0><<<dim3(2,500), dim3(256), 0, stream>>>(MEM,512,512, nullptr,0,0, wPROJm,512, PM,160, proj_b, nullptr,0, 160, 0);

  // pass 1: h1 recurrence (MEM now dead; B1 becomes h1_all)
  k_zero16<<<NB(BB*HH), dim3(256), 0, stream>>>(B1, BB*HH);
  k_rec<<<dim3(64), dim3(256), 0, stream>>>(wG1WHH, g1_bhh, GI, B1, nullptr, nullptr, 0, bar);

  // d2 = h1_all@att_wh^T + attpre  -> B3 (X2 dead)
  k_gemm<0,0><<<dim3(8,500), dim3(256), 0, stream>>>(B1+(size_t)BB*HH,1024,1024, nullptr,0,0, wATTWH,1024, B3,1024, nullptr, B2,1024, 1024, 0);

  // gi2 = d2@g2_wih^T + g2_bih
  k_gemm<0,0><<<dim3(24,500), dim3(256), 0, stream>>>(B3,1024,1024, nullptr,0,0, wG2WIH,1024, GI,3072, g2_bih, nullptr,0, 3072, 0);

  // pass 2: h2 recurrence in B2 (attpre dead), writes r2 = h2+d2 -> B1 (h1 dead)
  k_zero16<<<NB(BB*HH), dim3(256), 0, stream>>>(B2, BB*HH);
  k_rec<<<dim3(64), dim3(256), 0, stream>>>(wG2WHH, g2_bhh, GI, B2, B3, B1, 1024, bar);

  // gi3 = r2@g3_wih^T + g3_bih
  k_gemm<0,0><<<dim3(24,500), dim3(256), 0, stream>>>(B1,1024,1024, nullptr,0,0, wG3WIH,1024, GI,3072, g3_bih, nullptr,0, 3072, 0);

  // pass 3: h3 recurrence in B3 (d2 dead), writes r3 = h3+r2 -> B2 (h2 dead)
  k_zero16<<<NB(BB*HH), dim3(256), 0, stream>>>(B3, BB*HH);
  k_rec<<<dim3(64), dim3(256), 0, stream>>>(wG3WHH, g3_bhh, GI, B3, B1, B2, 1024, bar);

  // out[b,t,:] = r3@proj_wr^T + PM  (f32, remapped store)
  k_gemm<1,1><<<dim3(2,500), dim3(256), 0, stream>>>(B2,1024,1024, nullptr,0,0, wPROJr,1024, d_out,160, nullptr, PM,160, 160, 0);
}

// Round 3
// 36311.096 us; speedup vs baseline: 1.2668x; 1.2668x over previous
//
#include <hip/hip_runtime.h>
#include <hip/hip_bf16.h>
#include <stdint.h>

// Problem dims
#define TD   1000
#define BB   64
#define HH   1024
#define EE   512
#define MMEL 80
#define TMEL 2000
#define RTOT (TD*BB)   // 64000 rows, row index = t*64 + b

typedef __attribute__((ext_vector_type(8))) short short8;   // 8 bf16 (4 VGPRs)
typedef __attribute__((ext_vector_type(4))) float f32x4;

__device__ __forceinline__ float bf2f(uint16_t h){ return __uint_as_float(((uint32_t)h)<<16); }
__device__ __forceinline__ uint16_t f2bf(float f){
  uint32_t u = __float_as_uint(f);
  return (uint16_t)((u + 0x7fffu + ((u>>16)&1u)) >> 16);   // RTNE
}

__device__ __forceinline__ void async16(const void* g, void* l) {
  __builtin_amdgcn_global_load_lds((const __attribute__((address_space(1))) void*)g,
                                   (__attribute__((address_space(3))) void*)l, 16, 0, 0);
}

__device__ __forceinline__ f32x4 mfma16(short8 a, short8 b, f32x4 c){
  return __builtin_amdgcn_mfma_f32_16x16x32_bf16(a, b, c, 0, 0, 0);
}

// ---------------- small prep kernels ----------------

__global__ void k_zero16(uint16_t* p, int n){ int i=blockIdx.x*256+threadIdx.x; if(i<n) p[i]=0; }
__global__ void k_zero32(unsigned* p, int n){ int i=blockIdx.x*256+threadIdx.x; if(i<n) p[i]=0u; }
__global__ void k_fill(float* p, int n, float v){ int i=blockIdx.x*256+threadIdx.x; if(i<n) p[i]=v; }

// f32 -> bf16 slice/pad copy. dst[r, c] = (c<cols)? src[r*src_ld + col0 + c] : 0
__global__ void k_cast(const float* __restrict__ src, uint16_t* __restrict__ dst,
                       int rows, int src_ld, int col0, int cols, int dst_ld){
  int i = blockIdx.x*256 + threadIdx.x;
  if (i >= rows*dst_ld) return;
  int r = i/dst_ld, c = i - r*dst_ld;
  float v = (c < cols) ? src[(size_t)r*src_ld + col0 + c] : 0.f;
  dst[i] = f2bf(v);
}

// teacher-forced decoder inputs, padded K=96: row t*64+b, di[t]= t==0?0:dec[b, 2t-1, :]
__global__ void k_di(const float* __restrict__ dec, uint16_t* __restrict__ di){
  int i = blockIdx.x*256 + threadIdx.x;
  if (i >= RTOT*96) return;
  int row = i/96, c = i - row*96;
  int t = row>>6, b = row&63;
  float v = 0.f;
  if (c < MMEL && t > 0) v = dec[((size_t)b*TMEL + (2*t-1))*MMEL + c];
  di[i] = f2bf(v);
}

// pooled memory: MEM[t*64+b, e] = 0.5*(memorys[b,2t,e]+memorys[b,2t+1,e])
__global__ void k_mem(const float* __restrict__ mem, uint16_t* __restrict__ out){
  int i = blockIdx.x*256 + threadIdx.x;
  if (i >= RTOT*EE) return;
  int row = i/EE, e = i - row*EE;
  int t = row>>6, b = row&63;
  size_t base = ((size_t)b*TMEL + 2*t)*EE + e;
  out[i] = f2bf(0.5f*(mem[base] + mem[base+EE]));
}

// ---------------- tiled bf16 MFMA GEMM ----------------
// C[M,N] = [A1 | A2][M, K1+K2] @ B[N,K]^T (+bias)(+Dadd)(relu?)
// M = 64000 (500 full 128-tiles, blockIdx.y). OM: 0 bf16 linear, 1 f32 remap (b,t), 2 f32 linear.
// DT: Dadd dtype 0 bf16, 1 f32.

template<int OM, int DT>
__global__ __launch_bounds__(256)
void k_gemm(const uint16_t* __restrict__ A1p, int K1, int lda1,
            const uint16_t* __restrict__ A2p, int K2, int lda2,
            const uint16_t* __restrict__ Bw, int ldb,
            void* __restrict__ Cp, int ldc,
            const float* __restrict__ bias,
            const void* __restrict__ Dadd, int ldd,
            int N, int relu)
{
  __shared__ __align__(16) uint16_t As[128*32];
  __shared__ __align__(16) uint16_t Bs[128*32];
  const int tid = threadIdx.x;
  const int w = tid>>6, lane = tid&63;
  const int q = lane>>4, ln = lane&15;
  const int m0 = blockIdx.y*128, n0 = blockIdx.x*128;
  const int wr = (w&1)*64, wc = (w>>1)*64;
  const int srow = w*32 + (lane>>2);
  const int scol = (lane&3)*8;
  const uint16_t* A1g = A1p + (size_t)(m0+srow)*lda1 + scol;
  const uint16_t* A1g2 = A1g + (size_t)16*lda1;
  const uint16_t* A2g = A2p ? A2p + (size_t)(m0+srow)*lda2 + scol : nullptr;
  const uint16_t* A2g2 = A2p ? A2g + (size_t)16*lda2 : nullptr;
  int bn1 = n0+srow;     bn1 = bn1 < N ? bn1 : N-1;
  int bn2 = n0+srow+16;  bn2 = bn2 < N ? bn2 : N-1;
  const uint16_t* Bg  = Bw + (size_t)bn1*ldb + scol;
  const uint16_t* Bg2 = Bw + (size_t)bn2*ldb + scol;
  uint16_t* As0 = &As[(w*32)*32];
  uint16_t* As1 = &As[(w*32+16)*32];
  uint16_t* Bs0 = &Bs[(w*32)*32];
  uint16_t* Bs1 = &Bs[(w*32+16)*32];
  const int K = K1 + K2;

  f32x4 acc[4][4] = {};
  for (int kt=0; kt<K; kt+=32) {
    __syncthreads();
    if (kt < K1) { async16(A1g+kt, As0);  async16(A1g2+kt, As1); }
    else         { async16(A2g+(kt-K1), As0);  async16(A2g2+(kt-K1), As1); }
    async16(Bg+kt, Bs0);  async16(Bg2+kt, Bs1);
    __syncthreads();
    short8 af[4], bfr[4];
    #pragma unroll
    for (int i=0;i<4;++i) af[i]  = *(const short8*)&As[(wr+16*i+ln)*32 + q*8];
    #pragma unroll
    for (int j=0;j<4;++j) bfr[j] = *(const short8*)&Bs[(wc+16*j+ln)*32 + q*8];
    #pragma unroll
    for (int i=0;i<4;++i)
      #pragma unroll
      for (int j=0;j<4;++j)
        acc[i][j] = mfma16(af[i], bfr[j], acc[i][j]);
  }

  #pragma unroll
  for (int i=0;i<4;++i){
    #pragma unroll
    for (int j=0;j<4;++j){
      int col = n0 + wc + 16*j + ln;
      if (col >= N) continue;
      float bv = bias ? bias[col] : 0.f;
      #pragma unroll
      for (int r=0;r<4;++r){
        int row = m0 + wr + 16*i + 4*q + r;
        float v = acc[i][j][r] + bv;
        if (Dadd) {
          if (DT) v += ((const float*)Dadd)[(size_t)row*ldd + col];
          else    v += bf2f(((const uint16_t*)Dadd)[(size_t)row*ldd + col]);
        }
        if (relu) v = v > 0.f ? v : 0.f;
        if (OM==0) {
          ((uint16_t*)Cp)[(size_t)row*ldc + col] = f2bf(v);
        } else if (OM==1) {
          int t = row>>6, b = row&63;
          ((float*)Cp)[((size_t)b*TD + t)*ldc + col] = v;
        } else {
          ((float*)Cp)[(size_t)row*ldc + col] = v;
        }
      }
    }
  }
}

// ---------------- distributed flag barrier (64 blocks) ----------------
// Each block release-stores its own generation flag (own 128B line -> parallel,
// no cacheline ping-pong). Wave 0's 64 lanes each poll one peer flag; acquire
// fence AFTER observation so the L1/L2 invalidate cannot be refilled stale.

__device__ __forceinline__ void flagbar(unsigned* flags, int blk, unsigned target){
  __syncthreads();
  if (threadIdx.x < 64) {
    if (threadIdx.x == 0)
      __hip_atomic_store(flags + blk*32, target, __ATOMIC_RELEASE, __HIP_MEMORY_SCOPE_AGENT);
    unsigned* f = flags + threadIdx.x*32;
    while (__hip_atomic_load(f, __ATOMIC_RELAXED, __HIP_MEMORY_SCOPE_AGENT) < target)
      __builtin_amdgcn_s_sleep(1);
    __builtin_amdgcn_fence(__ATOMIC_ACQUIRE, "agent");
  }
  __syncthreads();
}

// ---------------- persistent GRU recurrence pass ----------------
// 64 blocks x 256 threads. Block owns 16 h-columns (j = blk*16 + ln) for all 64 batches.
// whh slice (3 gates x 16 cols x 1024 K) preloaded into registers.

__global__ __launch_bounds__(256,1)
void k_rec(const uint16_t* __restrict__ whh, const float* __restrict__ bhh,
           const uint16_t* __restrict__ gi, uint16_t* __restrict__ h_all,
           const uint16_t* __restrict__ radd, uint16_t* __restrict__ rout,
           int ld_rout, unsigned* flags)
{
  __shared__ __align__(16) float red[12288];   // 48 slots x 64 lanes x 4 regs
  const int tid = threadIdx.x;
  const int w = tid>>6, lane = tid&63;
  const int q = lane>>4, ln = lane&15;
  const int j = blockIdx.x*16 + ln;
  const float bh0 = bhh[j], bh1 = bhh[1024+j], bh2 = bhh[2048+j];

  short8 breg[3][8];
  #pragma unroll
  for (int g=0; g<3; ++g) {
    const uint16_t* Bp = whh + (size_t)(g*1024 + j)*1024 + (w*8)*32 + q*8;
    #pragma unroll
    for (int ks=0; ks<8; ++ks)
      breg[g][ks] = *(const short8*)(Bp + ks*32);
  }

  float hold[4] = {0.f,0.f,0.f,0.f};

  for (int t=0; t<TD; ++t) {
    const uint16_t* hp = h_all + (size_t)t*(BB*HH);
    f32x4 acc[3][4];
    #pragma unroll
    for (int g=0;g<3;++g)
      #pragma unroll
      for (int mt=0;mt<4;++mt) acc[g][mt] = (f32x4){0.f,0.f,0.f,0.f};

    #pragma unroll
    for (int ks=0; ks<8; ++ks) {
      const int k0 = (w*8+ks)*32 + q*8;
      #pragma unroll
      for (int mt=0; mt<4; ++mt) {
        short8 a = *(const short8*)(hp + (size_t)(16*mt+ln)*HH + k0);
        acc[0][mt] = mfma16(a, breg[0][ks], acc[0][mt]);
        acc[1][mt] = mfma16(a, breg[1][ks], acc[1][mt]);
        acc[2][mt] = mfma16(a, breg[2][ks], acc[2][mt]);
      }
    }

    #pragma unroll
    for (int g=0;g<3;++g)
      #pragma unroll
      for (int mt=0;mt<4;++mt)
        *(f32x4*)&red[((w*12 + g*4 + mt)*64 + lane)*4] = acc[g][mt];
    __syncthreads();

    f32x4 s0, s1, s2;
    s0 = *(const f32x4*)&red[((0*12 + 0*4 + w)*64 + lane)*4];
    s1 = *(const f32x4*)&red[((0*12 + 1*4 + w)*64 + lane)*4];
    s2 = *(const f32x4*)&red[((0*12 + 2*4 + w)*64 + lane)*4];
    #pragma unroll
    for (int kw=1;kw<4;++kw){
      s0 += *(const f32x4*)&red[((kw*12 + 0*4 + w)*64 + lane)*4];
      s1 += *(const f32x4*)&red[((kw*12 + 1*4 + w)*64 + lane)*4];
      s2 += *(const f32x4*)&red[((kw*12 + 2*4 + w)*64 + lane)*4];
    }

    #pragma unroll
    for (int r=0;r<4;++r){
      const int b = 16*w + 4*q + r;
      const size_t rowi = (size_t)t*BB + b;
      const size_t gb = rowi*3072;
      float ir  = bf2f(gi[gb + j]);
      float iz  = bf2f(gi[gb + 1024 + j]);
      float inn = bf2f(gi[gb + 2048 + j]);
      float rg = 1.f/(1.f + __expf(-(ir + s0[r] + bh0)));
      float zg = 1.f/(1.f + __expf(-(iz + s1[r] + bh1)));
      float nx = inn + rg*(s2[r] + bh2);
      float ng = 1.f - 2.f/(1.f + __expf(2.f*nx));   // tanh(nx)
      float hn = (1.f - zg)*ng + zg*hold[r];
      hold[r] = hn;
      h_all[(size_t)(t+1)*(BB*HH) + (size_t)b*HH + j] = f2bf(hn);
      if (rout) {
        float rv = hn + bf2f(radd[rowi*HH + j]);
        rout[rowi*(size_t)ld_rout + j] = f2bf(rv);
      }
    }
    if (t+1 < TD) flagbar(flags, blockIdx.x, (unsigned)(t+1));
  }
}

// ---------------- host launch ----------------

extern "C" void kernel_launch(void* const* d_in, const int* in_sizes, int n_in,
                              void* d_out, int out_size, void* d_ws, size_t ws_size,
                              hipStream_t stream)
{
  (void)in_sizes; (void)n_in;
  const float* memorys = (const float*)d_in[0];
  const float* decin   = (const float*)d_in[1];
  const float* pre_w1  = (const float*)d_in[3];
  const float* pre_b1  = (const float*)d_in[4];
  const float* pre_w2  = (const float*)d_in[5];
  const float* pre_b2  = (const float*)d_in[6];
  const float* g1_wih  = (const float*)d_in[7];
  const float* g1_whh  = (const float*)d_in[8];
  const float* g1_bih  = (const float*)d_in[9];
  const float* g1_bhh  = (const float*)d_in[10];
  const float* att_w   = (const float*)d_in[11];
  const float* att_b   = (const float*)d_in[12];
  const float* g2_wih  = (const float*)d_in[13];
  const float* g2_whh  = (const float*)d_in[14];
  const float* g2_bih  = (const float*)d_in[15];
  const float* g2_bhh  = (const float*)d_in[16];
  const float* g3_wih  = (const float*)d_in[17];
  const float* g3_whh  = (const float*)d_in[18];
  const float* g3_bih  = (const float*)d_in[19];
  const float* g3_bhh  = (const float*)d_in[20];
  const float* proj_w  = (const float*)d_in[21];
  const float* proj_b  = (const float*)d_in[22];

  uint16_t* ws = (uint16_t*)d_ws;
  size_t off = 0;
  auto alloc = [&](size_t n){ uint16_t* p = ws + off; off += (n + 127) & ~size_t(127); return p; };

  // weights (bf16)
  uint16_t* wG1WHH = alloc((size_t)3072*1024);
  uint16_t* wATTWH = alloc((size_t)1024*1024);
  uint16_t* wATTWM = alloc((size_t)1024*512);
  uint16_t* wG2WIH = alloc((size_t)3072*1024);
  uint16_t* wG2WHH = alloc((size_t)3072*1024);
  uint16_t* wG3WIH = alloc((size_t)3072*1024);
  uint16_t* wG3WHH = alloc((size_t)3072*1024);
  uint16_t* wG1WIH = alloc((size_t)3072*768);
  uint16_t* wPW1   = alloc((size_t)256*96);
  uint16_t* wPW2   = alloc((size_t)256*256);
  uint16_t* wPROJr = alloc((size_t)160*1024);
  uint16_t* wPROJm = alloc((size_t)160*512);

  float*    PM  = (float*)alloc((size_t)RTOT*160*2);       // f32 mem@projW_m^T + proj_b
  uint16_t* GI  = alloc((size_t)RTOT*3072);                // gi1 -> gi2 -> gi3
  uint16_t* B1  = alloc((size_t)(RTOT+BB)*1024);           // MEM -> h1_all -> R2A
  uint16_t* B2  = alloc((size_t)(RTOT+BB)*1024);           // attpre -> h2_all -> R3
  uint16_t* B3  = alloc((size_t)(RTOT+BB)*1024);           // X2 -> d2 -> h3_all
  unsigned* flags = (unsigned*)(ws + off); off += 3*64*32*2 + 256;

  // sub-lifetime aliases
  uint16_t* DI96 = GI;                       // 64000x96, dead before GI written
  uint16_t* X1   = GI + (size_t)6144000;     // 64000x256, dead before GI written
  uint16_t* MEM  = B1;                       // 64000x512
  uint16_t* X2   = B3;                       // 64000x256

  size_t need_bytes = off * 2;
  if (ws_size < need_bytes) {
    // diagnostic sentinel: encodes available workspace MB
    float v = 1048576.0f + (float)(ws_size >> 20);
    k_fill<<<dim3((out_size+255)/256), dim3(256), 0, stream>>>((float*)d_out, out_size, v);
    return;
  }

  auto NB = [](long long n){ return dim3((unsigned)((n+255)/256)); };

  // weight conversion / split / pad
  k_cast<<<NB(3072*1024), dim3(256), 0, stream>>>(g1_whh, wG1WHH, 3072, 1024, 0, 1024, 1024);
  k_cast<<<NB(1024*1024), dim3(256), 0, stream>>>(att_w,  wATTWH, 1024, 1536, 0, 1024, 1024);
  k_cast<<<NB(1024*512),  dim3(256), 0, stream>>>(att_w,  wATTWM, 1024, 1536, 1024, 512, 512);
  k_cast<<<NB(3072*1024), dim3(256), 0, stream>>>(g2_wih, wG2WIH, 3072, 1024, 0, 1024, 1024);
  k_cast<<<NB(3072*1024), dim3(256), 0, stream>>>(g2_whh, wG2WHH, 3072, 1024, 0, 1024, 1024);
  k_cast<<<NB(3072*1024), dim3(256), 0, stream>>>(g3_wih, wG3WIH, 3072, 1024, 0, 1024, 1024);
  k_cast<<<NB(3072*1024), dim3(256), 0, stream>>>(g3_whh, wG3WHH, 3072, 1024, 0, 1024, 1024);
  k_cast<<<NB(3072*768),  dim3(256), 0, stream>>>(g1_wih, wG1WIH, 3072, 768, 0, 768, 768);
  k_cast<<<NB(256*96),    dim3(256), 0, stream>>>(pre_w1, wPW1,   256, 80, 0, 80, 96);
  k_cast<<<NB(256*256),   dim3(256), 0, stream>>>(pre_w2, wPW2,   256, 256, 0, 256, 256);
  k_cast<<<NB(160*1024),  dim3(256), 0, stream>>>(proj_w, wPROJr, 160, 1536, 0, 1024, 1024);
  k_cast<<<NB(160*512),   dim3(256), 0, stream>>>(proj_w, wPROJm, 160, 1536, 1024, 512, 512);

  // inputs
  k_di <<<NB((long long)RTOT*96),  dim3(256), 0, stream>>>(decin, DI96);
  k_mem<<<NB((long long)RTOT*EE),  dim3(256), 0, stream>>>(memorys, MEM);
  k_zero32<<<dim3(24), dim3(256), 0, stream>>>(flags, 3*64*32);

  // prenet
  k_gemm<0,0><<<dim3(2,500), dim3(256), 0, stream>>>(DI96,96,96, nullptr,0,0, wPW1,96, X1,256, pre_b1, nullptr,0, 256, 1);
  k_gemm<0,0><<<dim3(2,500), dim3(256), 0, stream>>>(X1,256,256, nullptr,0,0, wPW2,256, X2,256, pre_b2, nullptr,0, 256, 1);

  // gi1 = [x|mem]@g1_wih^T + g1_bih
  k_gemm<0,0><<<dim3(24,500), dim3(256), 0, stream>>>(X2,256,256, MEM,512,512, wG1WIH,768, GI,3072, g1_bih, nullptr,0, 3072, 0);
  // attpre = mem@att_wm^T + att_b  -> B2
  k_gemm<0,0><<<dim3(8,500), dim3(256), 0, stream>>>(MEM,512,512, nullptr,0,0, wATTWM,512, B2,1024, att_b, nullptr,0, 1024, 0);
  // PM = mem@proj_wm^T + proj_b (f32)
  k_gemm<2,0><<<dim3(2,500), dim3(256), 0, stream>>>(MEM,512,512, nullptr,0,0, wPROJm,512, PM,160, proj_b, nullptr,0, 160, 0);

  // pass 1: h1 recurrence (MEM now dead; B1 becomes h1_all)
  k_zero16<<<NB(BB*HH), dim3(256), 0, stream>>>(B1, BB*HH);
  k_rec<<<dim3(64), dim3(256), 0, stream>>>(wG1WHH, g1_bhh, GI, B1, nullptr, nullptr, 0, flags);

  // d2 = h1_all@att_wh^T + attpre  -> B3 (X2 dead)
  k_gemm<0,0><<<dim3(8,500), dim3(256), 0, stream>>>(B1+(size_t)BB*HH,1024,1024, nullptr,0,0, wATTWH,1024, B3,1024, nullptr, B2,1024, 1024, 0);

  // gi2 = d2@g2_wih^T + g2_bih
  k_gemm<0,0><<<dim3(24,500), dim3(256), 0, stream>>>(B3,1024,1024, nullptr,0,0, wG2WIH,1024, GI,3072, g2_bih, nullptr,0, 3072, 0);

  // pass 2: h2 recurrence in B2 (attpre dead), writes r2 = h2+d2 -> B1 (h1 dead)
  k_zero16<<<NB(BB*HH), dim3(256), 0, stream>>>(B2, BB*HH);
  k_rec<<<dim3(64), dim3(256), 0, stream>>>(wG2WHH, g2_bhh, GI, B2, B3, B1, 1024, flags + 64*32);

  // gi3 = r2@g3_wih^T + g3_bih
  k_gemm<0,0><<<dim3(24,500), dim3(256), 0, stream>>>(B1,1024,1024, nullptr,0,0, wG3WIH,1024, GI,3072, g3_bih, nullptr,0, 3072, 0);

  // pass 3: h3 recurrence in B3 (d2 dead), writes r3 = h3+r2 -> B2 (h2 dead)
  k_zero16<<<NB(BB*HH), dim3(256), 0, stream>>>(B3, BB*HH);
  k_rec<<<dim3(64), dim3(256), 0, stream>>>(wG3WHH, g3_bhh, GI, B3, B1, B2, 1024, flags + 2*64*32);

  // out[b,t,:] = r3@proj_wr^T + PM  (f32, remapped store)
  k_gemm<1,1><<<dim3(2,500), dim3(256), 0, stream>>>(B2,1024,1024, nullptr,0,0, wPROJr,1024, d_out,160, nullptr, PM,160, 160, 0);
}